// Round 1
// baseline (18259.070 us; speedup 1.0000x reference)
//
#include <hip/hip_runtime.h>
#include <math.h>

typedef unsigned short u16;

#define T_STEPS 64
#define B_      256
#define EMB_    1024
#define ACT_    6
#define STOCH_  64
#define HID_    512
#define FEAT_   512
#define STATE_  576
#define G3      1536
#define TK      32
#define XPAD    68
#define WPAD    132
#define LOG2PI_ 1.8378770664093453

struct Params {
  const float *emb,*action,*reward,*eps;
  const float *bih,*bhh,*stb0,*stb1,*stb2,*epb0,*epb1,*epb2;
  const u16 *bWih,*bWhh,*bstW0,*bstW1,*bstW2,*bepW0,*bepW1,*bepW2;
  float *states;
  double *acc;   // [0]=kl [1]=emb [2]=reward
  float *out;
};

__device__ __forceinline__ float4 ld4(const float* p){ return *(const float4*)p; }
__device__ __forceinline__ float elu_f(float x){ return x > 0.f ? x : expm1f(x); }
__device__ __forceinline__ float sigmoid_f(float x){ return 1.f/(1.f+expf(-x)); }
__device__ __forceinline__ float softplus_f(float x){ return x > 20.f ? x : log1pf(expf(x)); }
__device__ __forceinline__ float blo(unsigned u){ return __uint_as_float(u << 16); }
__device__ __forceinline__ float bhi(unsigned u){ return __uint_as_float(u & 0xFFFF0000u); }
__device__ __forceinline__ float qred(float a){   // reduce over 4-lane cluster
  a += __shfl_xor(a, 1, 64);
  a += __shfl_xor(a, 2, 64);
  return a;
}
__device__ __forceinline__ double wave_sum(double v){
  #pragma unroll
  for (int o = 32; o > 0; o >>= 1) v += __shfl_down(v, o, 64);
  return v;
}

// ---------------- weight converters (fp32 -> bf16 RNE) — R5-proven ----------------
__global__ void convw_k(const float* __restrict__ s, u16* __restrict__ d, int n){
  const int i = blockIdx.x*256 + threadIdx.x;
  if (i < n){
    const unsigned u = __float_as_uint(s[i]);
    d[i] = (u16)((u + 0x7FFFu + ((u>>16)&1u)) >> 16);
  }
}
// Wih [1536][70] -> padded [1536][96] bf16 (zero pad)
__global__ void convwih_k(const float* __restrict__ s, u16* __restrict__ d){
  const int i = blockIdx.x*256 + threadIdx.x;   // < 1536*96
  const int n = i/96, k = i%96;
  u16 r = 0;
  if (k < 70){
    const unsigned u = __float_as_uint(s[n*70 + k]);
    r = (u16)((u + 0x7FFFu + ((u>>16)&1u)) >> 16);
  }
  d[i] = r;
}

// ---------------- scan GEMV cores: bf16 W via uint4 loads, fp32 x/accum ----------------
// 4-lane cluster, TWO output rows n0,n1 per pass sharing one x stream.
// lane l covers k = l*8 + 32*j; uint4 = 8 bf16: u32 low half = element k (LE).

template<int K>
__device__ __forceinline__ void gemv2b(const u16* __restrict__ W, const float* x,
                                       int n0, int n1, int l, float& y0, float& y1){
  const u16* w0 = W + (long)n0*K + l*8;
  const u16* w1 = W + (long)n1*K + l*8;
  const float* xr = x + l*8;
  float p0=0.f,p1=0.f,p2=0.f,p3=0.f, q0=0.f,q1=0.f,q2=0.f,q3=0.f;
  for (int j = 0; j < K/32; ++j){
    const uint4 a = *(const uint4*)(w0 + 32*j);
    const uint4 b = *(const uint4*)(w1 + 32*j);
    const float4 xa = ld4(xr + 32*j);
    const float4 xb = ld4(xr + 32*j + 4);
    p0 += blo(a.x)*xa.x + bhi(a.x)*xa.y;
    p1 += blo(a.y)*xa.z + bhi(a.y)*xa.w;
    p2 += blo(a.z)*xb.x + bhi(a.z)*xb.y;
    p3 += blo(a.w)*xb.z + bhi(a.w)*xb.w;
    q0 += blo(b.x)*xa.x + bhi(b.x)*xa.y;
    q1 += blo(b.y)*xa.z + bhi(b.y)*xa.w;
    q2 += blo(b.z)*xb.x + bhi(b.z)*xb.y;
    q3 += blo(b.w)*xb.z + bhi(b.w)*xb.w;
  }
  y0 = qred((p0+p1)+(p2+p3));
  y1 = qred((q0+q1)+(q2+q3));
}

// st0: K=1536 = 512 head (shared x = h_t) + 1024 tail (xA=emb_prev posterior, xB=pre_emb prior)
__device__ __forceinline__ void st0q(const u16* __restrict__ W, const float* xh,
                                     const float* xA, const float* xB,
                                     int n0, int n1, int l,
                                     float& pA0, float& pA1, float& pB0, float& pB1){
  const u16* w0 = W + (long)n0*G3 + l*8;
  const u16* w1 = W + (long)n1*G3 + l*8;
  float h0=0.f, h1=0.f;
  for (int j = 0; j < 16; ++j){
    const uint4 a = *(const uint4*)(w0 + 32*j);
    const uint4 b = *(const uint4*)(w1 + 32*j);
    const float4 xa = ld4(xh + l*8 + 32*j);
    const float4 xb = ld4(xh + l*8 + 32*j + 4);
    h0 += blo(a.x)*xa.x + bhi(a.x)*xa.y + blo(a.y)*xa.z + bhi(a.y)*xa.w
        + blo(a.z)*xb.x + bhi(a.z)*xb.y + blo(a.w)*xb.z + bhi(a.w)*xb.w;
    h1 += blo(b.x)*xa.x + bhi(b.x)*xa.y + blo(b.y)*xa.z + bhi(b.y)*xa.w
        + blo(b.z)*xb.x + bhi(b.z)*xb.y + blo(b.w)*xb.z + bhi(b.w)*xb.w;
  }
  float a0=0.f, a1=0.f, c0=0.f, c1=0.f;
  for (int j = 0; j < 32; ++j){
    const uint4 a = *(const uint4*)(w0 + 512 + 32*j);
    const uint4 b = *(const uint4*)(w1 + 512 + 32*j);
    const float4 va = ld4(xA + l*8 + 32*j);
    const float4 vb = ld4(xA + l*8 + 32*j + 4);
    const float4 wa = ld4(xB + l*8 + 32*j);
    const float4 wb = ld4(xB + l*8 + 32*j + 4);
    a0 += blo(a.x)*va.x + bhi(a.x)*va.y + blo(a.y)*va.z + bhi(a.y)*va.w
        + blo(a.z)*vb.x + bhi(a.z)*vb.y + blo(a.w)*vb.z + bhi(a.w)*vb.w;
    a1 += blo(b.x)*va.x + bhi(b.x)*va.y + blo(b.y)*va.z + bhi(b.y)*va.w
        + blo(b.z)*vb.x + bhi(b.z)*vb.y + blo(b.w)*vb.z + bhi(b.w)*vb.w;
    c0 += blo(a.x)*wa.x + bhi(a.x)*wa.y + blo(a.y)*wa.z + bhi(a.y)*wa.w
        + blo(a.z)*wb.x + bhi(a.z)*wb.y + blo(a.w)*wb.z + bhi(a.w)*wb.w;
    c1 += blo(b.x)*wa.x + bhi(b.x)*wa.y + blo(b.y)*wa.z + bhi(b.y)*wa.w
        + blo(b.z)*wb.x + bhi(b.z)*wb.y + blo(b.w)*wb.z + bhi(b.w)*wb.w;
  }
  pA0 = qred(h0 + a0); pA1 = qred(h1 + a1);
  pB0 = qred(h0 + c0); pB1 = qred(h1 + c1);
}

// st1/st2: K=512, 2 rows x 2 x-streams (posterior xA / prior xB), one W stream pair.
__device__ __forceinline__ void quad2b(const u16* __restrict__ W,
                                       const float* xA, const float* xB,
                                       int n0, int n1, int l,
                                       float& pA0, float& pA1, float& pB0, float& pB1){
  const u16* w0 = W + (long)n0*512 + l*8;
  const u16* w1 = W + (long)n1*512 + l*8;
  float a0=0.f, a1=0.f, c0=0.f, c1=0.f;
  for (int j = 0; j < 16; ++j){
    const uint4 a = *(const uint4*)(w0 + 32*j);
    const uint4 b = *(const uint4*)(w1 + 32*j);
    const float4 va = ld4(xA + l*8 + 32*j);
    const float4 vb = ld4(xA + l*8 + 32*j + 4);
    const float4 wa = ld4(xB + l*8 + 32*j);
    const float4 wb = ld4(xB + l*8 + 32*j + 4);
    a0 += blo(a.x)*va.x + bhi(a.x)*va.y + blo(a.y)*va.z + bhi(a.y)*va.w
        + blo(a.z)*vb.x + bhi(a.z)*vb.y + blo(a.w)*vb.z + bhi(a.w)*vb.w;
    a1 += blo(b.x)*va.x + bhi(b.x)*va.y + blo(b.y)*va.z + bhi(b.y)*va.w
        + blo(b.z)*vb.x + bhi(b.z)*vb.y + blo(b.w)*vb.z + bhi(b.w)*vb.w;
    c0 += blo(a.x)*wa.x + bhi(a.x)*wa.y + blo(a.y)*wa.z + bhi(a.y)*wa.w
        + blo(a.z)*wb.x + bhi(a.z)*wb.y + blo(a.w)*wb.z + bhi(a.w)*wb.w;
    c1 += blo(b.x)*wa.x + bhi(b.x)*wa.y + blo(b.y)*wa.z + bhi(b.y)*wa.w
        + blo(b.z)*wb.x + bhi(b.z)*wb.y + blo(b.w)*wb.z + bhi(b.w)*wb.w;
  }
  pA0 = qred(a0); pA1 = qred(a1);
  pB0 = qred(c0); pB1 = qred(c1);
}

// ---------------- scan kernel: one block per batch row ------------------------------
// R7: 1024 threads (16 waves/CU = 4 waves/SIMD, was 2) to hide L2/L3 weight-load
// latency; 256 clusters -> per-phase pass counts halve. Same math/numerics as R6.
__global__ void __launch_bounds__(1024, 4) scan_kernel(Params p)
{
  const int tid = threadIdx.x;
  const int r = blockIdx.x;
  const int c = tid >> 2, l = tid & 3;   // 256 clusters of 4 lanes

  __shared__ __align__(16) float hs[STATE_];   // [h(512) | s(64)]
  __shared__ __align__(16) float sa[96];       // [s(64) | a(6) | 0-pad]
  __shared__ __align__(16) float ep_[EMB_];
  __shared__ __align__(16) float pe0[512], pe1[512];
  __shared__ __align__(16) float pemb[EMB_];
  __shared__ __align__(16) float gi[G3], gh[G3];
  __shared__ __align__(16) float po0[512], po1[512], pr0[512], pr1[512];
  __shared__ __align__(16) float po2[128], pr2[128];

  double klacc = 0.0;
  if (tid < STATE_) hs[tid] = 0.f;
  __syncthreads();

  for (int t = 0; t < T_STEPS; ++t){
    // ---- prologue: emb_prev row + sa = [s_{t-1} | a_t | 0] ----
    {
      const long eb = ((long)(t > 0 ? t-1 : 0)*B_ + r)*EMB_;
      ep_[tid] = p.emb[eb + tid];
      if (tid < 96){
        float v = 0.f;
        if (tid < 64)      v = hs[512 + tid];
        else if (tid < 70) v = p.action[((long)t*B_ + r)*ACT_ + (tid - 64)];
        sa[tid] = v;
      }
    }
    __syncthreads();
    // ---- S_A: pe0 (1p), gh (3p), gi (3p) — all read h/s_{t-1} ----
    {
      const int n0 = c, n1 = c + 256;
      float y0, y1;
      gemv2b<STATE_>(p.bepW0, hs, n0, n1, l, y0, y1);
      if (l == 0){
        pe0[n0] = elu_f(y0 + p.epb0[n0]);
        pe0[n1] = elu_f(y1 + p.epb0[n1]);
      }
    }
    for (int ps = 0; ps < 3; ++ps){
      const int n0 = ps*512 + c, n1 = n0 + 256;
      float y0, y1;
      gemv2b<HID_>(p.bWhh, hs, n0, n1, l, y0, y1);
      if (l == 0){
        gh[n0] = y0 + p.bhh[n0];
        gh[n1] = y1 + p.bhh[n1];
      }
    }
    for (int ps = 0; ps < 3; ++ps){
      const int n0 = ps*512 + c, n1 = n0 + 256;
      float y0, y1;
      gemv2b<96>(p.bWih, sa, n0, n1, l, y0, y1);
      if (l == 0){
        gi[n0] = y0 + p.bih[n0];
        gi[n1] = y1 + p.bih[n1];
      }
    }
    __syncthreads();
    // ---- S_B: pe1 (1p) ----
    {
      const int n0 = c, n1 = c + 256;
      float y0, y1;
      gemv2b<FEAT_>(p.bepW1, pe0, n0, n1, l, y0, y1);
      if (l == 0){
        pe1[n0] = elu_f(y0 + p.epb1[n0]);
        pe1[n1] = elu_f(y1 + p.epb1[n1]);
      }
    }
    __syncthreads();
    // ---- S_C: pemb (2p) + GRU combine -> h_t (disjoint LDS) ----
    for (int ps = 0; ps < 2; ++ps){
      const int n0 = ps*512 + c, n1 = n0 + 256;
      float y0, y1;
      gemv2b<FEAT_>(p.bepW2, pe1, n0, n1, l, y0, y1);
      if (l == 0){
        pemb[n0] = y0 + p.epb2[n0];
        pemb[n1] = y1 + p.epb2[n1];
      }
    }
    if (tid < 512){
      const int j = tid;
      const float ir = gi[j], iz = gi[512+j], in_ = gi[1024+j];
      const float hr = gh[j], hz = gh[512+j], hn  = gh[1024+j];
      const float rr = sigmoid_f(ir + hr);
      const float z  = sigmoid_f(iz + hz);
      const float nn = tanhf(in_ + rr*hn);
      const float hv = (1.f - z)*nn + z*hs[j];
      hs[j] = hv;
      p.states[((long)t*B_ + r)*STATE_ + j] = hv;
    }
    __syncthreads();
    // ---- S_D: st0 quad (1p) ----
    {
      const int n0 = c, n1 = c + 256;
      float pA0, pA1, pB0, pB1;
      st0q(p.bstW0, hs, ep_, pemb, n0, n1, l, pA0, pA1, pB0, pB1);
      if (l == 0){
        po0[n0] = elu_f(pA0 + p.stb0[n0]);
        po0[n1] = elu_f(pA1 + p.stb0[n1]);
        pr0[n0] = elu_f(pB0 + p.stb0[n0]);
        pr0[n1] = elu_f(pB1 + p.stb0[n1]);
      }
    }
    __syncthreads();
    // ---- S_E: st1 quad (1p) ----
    {
      const int n0 = c, n1 = c + 256;
      float pA0, pA1, pB0, pB1;
      quad2b(p.bstW1, po0, pr0, n0, n1, l, pA0, pA1, pB0, pB1);
      if (l == 0){
        po1[n0] = elu_f(pA0 + p.stb1[n0]);
        po1[n1] = elu_f(pA1 + p.stb1[n1]);
        pr1[n0] = elu_f(pB0 + p.stb1[n0]);
        pr1[n1] = elu_f(pB1 + p.stb1[n1]);
      }
    }
    __syncthreads();
    // ---- S_F: st2 quad (1p, clusters 0..63) ----
    if (c < 64){
      const int n0 = c, n1 = c + 64;
      float pA0, pA1, pB0, pB1;
      quad2b(p.bstW2, po1, pr1, n0, n1, l, pA0, pA1, pB0, pB1);
      if (l == 0){
        po2[n0] = pA0 + p.stb2[n0];
        po2[n1] = pA1 + p.stb2[n1];
        pr2[n0] = pB0 + p.stb2[n0];
        pr2[n1] = pB1 + p.stb2[n1];
      }
    }
    __syncthreads();
    // ---- S_G: KL(t) + sample s_t ----
    if (tid < 64){
      const int j = tid;
      const float qmu = po2[j],  qsr = po2[64+j];
      const float pmu = pr2[j],  psr = pr2[64+j];
      const float qstd = softplus_f(qsr) + 1e-4f;
      const float pstd = softplus_f(psr) + 1e-4f;
      const float dm = qmu - pmu;
      klacc += (double)(logf(pstd/qstd) + (qstd*qstd + dm*dm)/(2.f*pstd*pstd) - 0.5f);
      const float sv = qmu + qstd * p.eps[((long)t*B_ + r)*STOCH_ + j];
      hs[512 + j] = sv;
      p.states[((long)t*B_ + r)*STATE_ + 512 + j] = sv;
    }
    __syncthreads();
  }

  if (tid < 64){
    const double s = wave_sum(klacc);
    if (tid == 0) atomicAdd(&p.acc[0], s);
  }
}

// ---------------- tail head kernels (R4/R6-proven, byte-identical) ----------------

struct SmemT { float X[2][TK][XPAD]; float W[2][TK][WPAD]; };

template<class XLD, class WLD>
__device__ __forceinline__ void gemm_tile(SmemT* sm, XLD xld, WLD wld, int nkt, float acc[4][4])
{
  const int tid = threadIdx.x;
  const int r0 = (tid >> 5) * 4;
  const int c0 = (tid & 31) * 4;
  const int sr = tid & 255;
  const int lr = sr >> 2, q = sr & 3;
  const bool lo = tid < 256;
  float4 xa, xb, wa, wb;
  if (lo) { xa = xld(lr, q*4);      xb = xld(lr, 16 + q*4);
            wa = wld(64+lr, q*4);   wb = wld(64+lr, 16 + q*4); }
  else    { wa = wld(lr, q*4);      wb = wld(lr, 16 + q*4); }
  int cur = 0;
  #pragma unroll
  for (int c = 0; c < 4; ++c) {
    if (lo) {
      sm->X[0][q*4+c][lr]      = ((const float*)&xa)[c];
      sm->X[0][16+q*4+c][lr]   = ((const float*)&xb)[c];
      sm->W[0][q*4+c][64+lr]   = ((const float*)&wa)[c];
      sm->W[0][16+q*4+c][64+lr]= ((const float*)&wb)[c];
    } else {
      sm->W[0][q*4+c][lr]      = ((const float*)&wa)[c];
      sm->W[0][16+q*4+c][lr]   = ((const float*)&wb)[c];
    }
  }
  for (int kt = 1; kt < nkt; ++kt) {
    __syncthreads();
    const int kb = kt*TK;
    if (lo) { xa = xld(lr, kb + q*4);    xb = xld(lr, kb + 16 + q*4);
              wa = wld(64+lr, kb + q*4); wb = wld(64+lr, kb + 16 + q*4); }
    else    { wa = wld(lr, kb + q*4);    wb = wld(lr, kb + 16 + q*4); }
    #pragma unroll
    for (int kk = 0; kk < TK; ++kk) {
      const float4 xv = *(const float4*)&sm->X[cur][kk][r0];
      const float4 wv = *(const float4*)&sm->W[cur][kk][c0];
      const float xs_[4] = {xv.x,xv.y,xv.z,xv.w};
      const float ws_[4] = {wv.x,wv.y,wv.z,wv.w};
      #pragma unroll
      for (int i = 0; i < 4; ++i)
        #pragma unroll
        for (int j = 0; j < 4; ++j) acc[i][j] += xs_[i]*ws_[j];
    }
    const int nxt = cur ^ 1;
    #pragma unroll
    for (int c = 0; c < 4; ++c) {
      if (lo) {
        sm->X[nxt][q*4+c][lr]      = ((const float*)&xa)[c];
        sm->X[nxt][16+q*4+c][lr]   = ((const float*)&xb)[c];
        sm->W[nxt][q*4+c][64+lr]   = ((const float*)&wa)[c];
        sm->W[nxt][16+q*4+c][64+lr]= ((const float*)&wb)[c];
      } else {
        sm->W[nxt][q*4+c][lr]      = ((const float*)&wa)[c];
        sm->W[nxt][16+q*4+c][lr]   = ((const float*)&wb)[c];
      }
    }
    cur = nxt;
  }
  __syncthreads();
  #pragma unroll
  for (int kk = 0; kk < TK; ++kk) {
    const float4 xv = *(const float4*)&sm->X[cur][kk][r0];
    const float4 wv = *(const float4*)&sm->W[cur][kk][c0];
    const float xs_[4] = {xv.x,xv.y,xv.z,xv.w};
    const float ws_[4] = {wv.x,wv.y,wv.z,wv.w};
    #pragma unroll
    for (int i = 0; i < 4; ++i)
      #pragma unroll
      for (int j = 0; j < 4; ++j) acc[i][j] += xs_[i]*ws_[j];
  }
}

__device__ __forceinline__ void store_tile(const float acc[4][4], const float* bias,
                                           float* C, int ldc, int row0, int col0, bool act)
{
  const int tid = threadIdx.x;
  const int r0 = (tid>>5)*4, c0 = (tid&31)*4;
  const float4 bi = ld4(bias + col0 + c0);
  #pragma unroll
  for (int i = 0; i < 4; ++i) {
    float4 v;
    v.x = acc[i][0] + bi.x; v.y = acc[i][1] + bi.y;
    v.z = acc[i][2] + bi.z; v.w = acc[i][3] + bi.w;
    if (act) { v.x=elu_f(v.x); v.y=elu_f(v.y); v.z=elu_f(v.z); v.w=elu_f(v.w); }
    *(float4*)&C[(long)(row0+r0+i)*ldc + col0 + c0] = v;
  }
}

__global__ void __launch_bounds__(512) mlp_gemm(const float* __restrict__ X, int ldx,
                                                const float* __restrict__ W, int K,
                                                const float* __restrict__ bias,
                                                float* __restrict__ Y, int ldy,
                                                int NT, int act)
{
  __shared__ SmemT sm;
  const int u = blockIdx.x;
  const int mt = u / NT, nt = u % NT;
  float acc[4][4] = {};
  auto xld = [&](int r,int k){ return ld4(X + (long)(mt*64+r)*ldx + k); };
  auto wld = [&](int n,int k){ return ld4(W + (long)(nt*128+n)*K + k); };
  gemm_tile(&sm, xld, wld, K/TK, acc);
  store_tile(acc, bias, Y, ldy, mt*64, nt*128, act != 0);
}

__device__ __forceinline__ double wave_sum_d(double v){
  #pragma unroll
  for (int o = 32; o > 0; o >>= 1) v += __shfl_down(v, o, 64);
  return v;
}

__global__ void __launch_bounds__(512) emb_loss_k(const float* __restrict__ X,
                                                  const float* __restrict__ W,
                                                  const float* __restrict__ bias,
                                                  const float* __restrict__ tgt,
                                                  double* accp)
{
  __shared__ SmemT sm;
  const int u = blockIdx.x;
  const int mt = u / 8, nt = u % 8;
  float acc[4][4] = {};
  auto xld = [&](int r,int k){ return ld4(X + (long)(mt*64+r)*FEAT_ + k); };
  auto wld = [&](int n,int k){ return ld4(W + (long)(nt*128+n)*FEAT_ + k); };
  gemm_tile(&sm, xld, wld, FEAT_/TK, acc);
  const int tid = threadIdx.x;
  const int r0 = (tid>>5)*4, c0 = (tid&31)*4;
  const float4 bi = ld4(bias + nt*128 + c0);
  double ls = 0.0;
  #pragma unroll
  for (int i = 0; i < 4; ++i) {
    const float4 tv = ld4(tgt + (long)(mt*64+r0+i)*EMB_ + nt*128 + c0);
    const float d0 = tv.x - (acc[i][0]+bi.x);
    const float d1 = tv.y - (acc[i][1]+bi.y);
    const float d2 = tv.z - (acc[i][2]+bi.z);
    const float d3 = tv.w - (acc[i][3]+bi.w);
    ls += 0.5*((double)d0*d0 + (double)d1*d1 + (double)d2*d2 + (double)d3*d3);
  }
  ls = wave_sum_d(ls);
  if ((tid & 63) == 0) atomicAdd(accp, ls);
}

__global__ void __launch_bounds__(512) rp_loss_k(const float* __restrict__ h2,
                                                 const float* __restrict__ W2,
                                                 const float* __restrict__ b2,
                                                 const float* __restrict__ reward,
                                                 double* accp)
{
  const int tid = threadIdx.x;
  const int lane = tid & 63;
  const int wid = blockIdx.x*8 + (tid >> 6);
  double ls = 0.0;
  for (int row = wid; row < 4096; row += 512) {
    float part = 0.f;
    for (int k = lane*4; k < FEAT_; k += 64*4) {
      const float4 hv = ld4(h2 + (long)row*FEAT_ + k);
      const float4 wv = ld4(W2 + k);
      part += hv.x*wv.x + hv.y*wv.y + hv.z*wv.z + hv.w*wv.w;
    }
    #pragma unroll
    for (int o = 32; o > 0; o >>= 1) part += __shfl_down(part, o, 64);
    if (lane == 0) {
      const float mu = part + b2[0];
      const float d = reward[row] - mu;
      ls += 0.5 * (double)d * (double)d;
    }
  }
  if (lane == 0) atomicAdd(accp, ls);
}

__global__ void final_k(const double* acc, float* out)
{
  const double tot = (acc[0] + acc[1] + acc[2]) / (double)(T_STEPS * B_)
                   + 512.0 * LOG2PI_ + 0.5 * LOG2PI_;
  out[0] = (float)tot;
}

extern "C" void kernel_launch(void* const* d_in, const int* in_sizes, int n_in,
                              void* d_out, int out_size, void* d_ws, size_t ws_size,
                              hipStream_t stream) {
  const float* emb    = (const float*)d_in[0];
  const float* action = (const float*)d_in[1];
  const float* reward = (const float*)d_in[2];
  const float* eps    = (const float*)d_in[3];
  const float* Wih  = (const float*)d_in[4];  const float* bih  = (const float*)d_in[5];
  const float* Whh  = (const float*)d_in[6];  const float* bhh  = (const float*)d_in[7];
  const float* stW0 = (const float*)d_in[8];  const float* stb0 = (const float*)d_in[9];
  const float* stW1 = (const float*)d_in[10]; const float* stb1 = (const float*)d_in[11];
  const float* stW2 = (const float*)d_in[12]; const float* stb2 = (const float*)d_in[13];
  const float* epW0 = (const float*)d_in[14]; const float* epb0 = (const float*)d_in[15];
  const float* epW1 = (const float*)d_in[16]; const float* epb1 = (const float*)d_in[17];
  const float* epW2 = (const float*)d_in[18]; const float* epb2 = (const float*)d_in[19];
  const float* rpW0 = (const float*)d_in[20]; const float* rpb0 = (const float*)d_in[21];
  const float* rpW1 = (const float*)d_in[22]; const float* rpb1 = (const float*)d_in[23];
  const float* rpW2 = (const float*)d_in[24]; const float* rpb2 = (const float*)d_in[25];

  double* acc = (double*)d_ws;
  float* f = (float*)((char*)d_ws + 256);
  float* states = f;  f += (long)16384 * STATE_;
  float* h1 = f;      f += (long)4096 * FEAT_;
  float* h2 = f;      f += (long)4096 * FEAT_;
  u16* bw = (u16*)f;
  u16* bepW0 = bw;    bw += 294912;
  u16* bepW1 = bw;    bw += 262144;
  u16* bepW2 = bw;    bw += 524288;
  u16* bWhh  = bw;    bw += 786432;
  u16* bstW0 = bw;    bw += 786432;
  u16* bstW1 = bw;    bw += 262144;
  u16* bstW2 = bw;    bw += 65536;
  u16* bWih  = bw;    bw += 147456;
  // total ws ~58 MB (< 64 MiB cap inferred from R2 launch failure)

  hipMemsetAsync(d_ws, 0, 256, stream);

  convw_k<<<(294912+255)/256, 256, 0, stream>>>(epW0, bepW0, 294912);
  convw_k<<<(262144+255)/256, 256, 0, stream>>>(epW1, bepW1, 262144);
  convw_k<<<(524288+255)/256, 256, 0, stream>>>(epW2, bepW2, 524288);
  convw_k<<<(786432+255)/256, 256, 0, stream>>>(Whh,  bWhh,  786432);
  convw_k<<<(786432+255)/256, 256, 0, stream>>>(stW0, bstW0, 786432);
  convw_k<<<(262144+255)/256, 256, 0, stream>>>(stW1, bstW1, 262144);
  convw_k<<<(65536+255)/256,  256, 0, stream>>>(stW2, bstW2, 65536);
  convwih_k<<<(147456+255)/256, 256, 0, stream>>>(Wih, bWih);

  Params p;
  p.emb = emb; p.action = action; p.reward = reward; p.eps = eps;
  p.bih = bih; p.bhh = bhh;
  p.stb0 = stb0; p.stb1 = stb1; p.stb2 = stb2;
  p.epb0 = epb0; p.epb1 = epb1; p.epb2 = epb2;
  p.bWih = bWih; p.bWhh = bWhh;
  p.bstW0 = bstW0; p.bstW1 = bstW1; p.bstW2 = bstW2;
  p.bepW0 = bepW0; p.bepW1 = bepW1; p.bepW2 = bepW2;
  p.states = states;
  p.acc = acc;
  p.out = (float*)d_out;

  scan_kernel<<<B_, 1024, 0, stream>>>(p);

  for (int ch = 0; ch < 4; ++ch) {
    const float* xs = states + (long)ch*4096*STATE_;
    mlp_gemm<<<64*4, 512, 0, stream>>>(xs, STATE_, epW0, STATE_, epb0, h1, FEAT_, 4, 1);
    mlp_gemm<<<64*4, 512, 0, stream>>>(h1, FEAT_, epW1, FEAT_, epb1, h2, FEAT_, 4, 1);
    emb_loss_k<<<64*8, 512, 0, stream>>>(h2, epW2, epb2, emb + (long)ch*4096*EMB_, acc + 1);
  }
  for (int ch = 0; ch < 4; ++ch) {
    const float* xs = states + (long)ch*4096*STATE_;
    mlp_gemm<<<64*4, 512, 0, stream>>>(xs, STATE_, rpW0, STATE_, rpb0, h1, FEAT_, 4, 1);
    mlp_gemm<<<64*4, 512, 0, stream>>>(h1, FEAT_, rpW1, FEAT_, rpb1, h2, FEAT_, 4, 1);
    rp_loss_k<<<64, 512, 0, stream>>>(h2, rpW2, rpb2, reward + (long)ch*4096, acc + 2);
  }
  final_k<<<1, 1, 0, stream>>>(acc, p.out);
}

// Round 2
// 8454.781 us; speedup vs baseline: 2.1596x; 2.1596x over previous
//
#include <hip/hip_runtime.h>
#include <math.h>

typedef unsigned short u16;
typedef __attribute__((ext_vector_type(8))) short bf16x8;
typedef __attribute__((ext_vector_type(4))) float f32x4;

#define T_STEPS 64
#define B_      256
#define EMB_    1024
#define ACT_    6
#define STOCH_  64
#define HID_    512
#define FEAT_   512
#define STATE_  576
#define G3      1536
#define LOG2PI_ 1.8378770664093453

struct Params {
  const float *emb,*action,*reward,*eps;
  const float *bih,*bhh,*stb0,*stb1,*stb2,*epb0,*epb1,*epb2;
  const u16 *bWih,*bWhh,*bstW0,*bstW1,*bstW2,*bepW0,*bepW1,*bepW2;
  u16 *states;            // bf16 [T*B][STATE_] for MFMA tail
  double *acc;            // [0]=kl [1]=emb [2]=reward
  float *out;
};

__device__ __forceinline__ float4 ld4(const float* p){ return *(const float4*)p; }
__device__ __forceinline__ float elu_f(float x){ return x > 0.f ? x : expm1f(x); }
__device__ __forceinline__ float sigmoid_f(float x){ return 1.f/(1.f+expf(-x)); }
__device__ __forceinline__ float softplus_f(float x){ return x > 20.f ? x : log1pf(expf(x)); }
__device__ __forceinline__ float blo(unsigned u){ return __uint_as_float(u << 16); }
__device__ __forceinline__ float bhi(unsigned u){ return __uint_as_float(u & 0xFFFF0000u); }
__device__ __forceinline__ u16 f2bf(float x){     // fp32 -> bf16 RNE
  const unsigned u = __float_as_uint(x);
  return (u16)((u + 0x7FFFu + ((u>>16)&1u)) >> 16);
}
__device__ __forceinline__ float qred(float a){   // reduce over 4-lane cluster
  a += __shfl_xor(a, 1, 64);
  a += __shfl_xor(a, 2, 64);
  return a;
}
__device__ __forceinline__ double wave_sum(double v){
  #pragma unroll
  for (int o = 32; o > 0; o >>= 1) v += __shfl_down(v, o, 64);
  return v;
}

// ---------------- weight converters (fp32 -> bf16 RNE) — R5-proven ----------------
__global__ void convw_k(const float* __restrict__ s, u16* __restrict__ d, int n){
  const int i = blockIdx.x*256 + threadIdx.x;
  if (i < n){
    const unsigned u = __float_as_uint(s[i]);
    d[i] = (u16)((u + 0x7FFFu + ((u>>16)&1u)) >> 16);
  }
}
// Wih [1536][70] -> padded [1536][96] bf16 (zero pad)
__global__ void convwih_k(const float* __restrict__ s, u16* __restrict__ d){
  const int i = blockIdx.x*256 + threadIdx.x;   // < 1536*96
  const int n = i/96, k = i%96;
  u16 r = 0;
  if (k < 70){
    const unsigned u = __float_as_uint(s[n*70 + k]);
    r = (u16)((u + 0x7FFFu + ((u>>16)&1u)) >> 16);
  }
  d[i] = r;
}

// ---------------- scan GEMV cores: bf16 W via uint4 loads, fp32 x/accum ----------------
// 4-lane cluster, TWO output rows n0,n1 per pass sharing one x stream.
// lane l covers k = l*8 + 32*j; uint4 = 8 bf16: u32 low half = element k (LE).

template<int K>
__device__ __forceinline__ void gemv2b(const u16* __restrict__ W, const float* x,
                                       int n0, int n1, int l, float& y0, float& y1){
  const u16* w0 = W + (long)n0*K + l*8;
  const u16* w1 = W + (long)n1*K + l*8;
  const float* xr = x + l*8;
  float p0=0.f,p1=0.f,p2=0.f,p3=0.f, q0=0.f,q1=0.f,q2=0.f,q3=0.f;
  for (int j = 0; j < K/32; ++j){
    const uint4 a = *(const uint4*)(w0 + 32*j);
    const uint4 b = *(const uint4*)(w1 + 32*j);
    const float4 xa = ld4(xr + 32*j);
    const float4 xb = ld4(xr + 32*j + 4);
    p0 += blo(a.x)*xa.x + bhi(a.x)*xa.y;
    p1 += blo(a.y)*xa.z + bhi(a.y)*xa.w;
    p2 += blo(a.z)*xb.x + bhi(a.z)*xb.y;
    p3 += blo(a.w)*xb.z + bhi(a.w)*xb.w;
    q0 += blo(b.x)*xa.x + bhi(b.x)*xa.y;
    q1 += blo(b.y)*xa.z + bhi(b.y)*xa.w;
    q2 += blo(b.z)*xb.x + bhi(b.z)*xb.y;
    q3 += blo(b.w)*xb.z + bhi(b.w)*xb.w;
  }
  y0 = qred((p0+p1)+(p2+p3));
  y1 = qred((q0+q1)+(q2+q3));
}

// st0: K=1536 = 512 head (shared x = h_t) + 1024 tail (xA=emb_prev posterior, xB=pre_emb prior)
__device__ __forceinline__ void st0q(const u16* __restrict__ W, const float* xh,
                                     const float* xA, const float* xB,
                                     int n0, int n1, int l,
                                     float& pA0, float& pA1, float& pB0, float& pB1){
  const u16* w0 = W + (long)n0*G3 + l*8;
  const u16* w1 = W + (long)n1*G3 + l*8;
  float h0=0.f, h1=0.f;
  for (int j = 0; j < 16; ++j){
    const uint4 a = *(const uint4*)(w0 + 32*j);
    const uint4 b = *(const uint4*)(w1 + 32*j);
    const float4 xa = ld4(xh + l*8 + 32*j);
    const float4 xb = ld4(xh + l*8 + 32*j + 4);
    h0 += blo(a.x)*xa.x + bhi(a.x)*xa.y + blo(a.y)*xa.z + bhi(a.y)*xa.w
        + blo(a.z)*xb.x + bhi(a.z)*xb.y + blo(a.w)*xb.z + bhi(a.w)*xb.w;
    h1 += blo(b.x)*xa.x + bhi(b.x)*xa.y + blo(b.y)*xa.z + bhi(b.y)*xa.w
        + blo(b.z)*xb.x + bhi(b.z)*xb.y + blo(b.w)*xb.z + bhi(b.w)*xb.w;
  }
  float a0=0.f, a1=0.f, c0=0.f, c1=0.f;
  for (int j = 0; j < 32; ++j){
    const uint4 a = *(const uint4*)(w0 + 512 + 32*j);
    const uint4 b = *(const uint4*)(w1 + 512 + 32*j);
    const float4 va = ld4(xA + l*8 + 32*j);
    const float4 vb = ld4(xA + l*8 + 32*j + 4);
    const float4 wa = ld4(xB + l*8 + 32*j);
    const float4 wb = ld4(xB + l*8 + 32*j + 4);
    a0 += blo(a.x)*va.x + bhi(a.x)*va.y + blo(a.y)*va.z + bhi(a.y)*va.w
        + blo(a.z)*vb.x + bhi(a.z)*vb.y + blo(a.w)*vb.z + bhi(a.w)*vb.w;
    a1 += blo(b.x)*va.x + bhi(b.x)*va.y + blo(b.y)*va.z + bhi(b.y)*va.w
        + blo(b.z)*vb.x + bhi(b.z)*vb.y + blo(b.w)*vb.z + bhi(b.w)*vb.w;
    c0 += blo(a.x)*wa.x + bhi(a.x)*wa.y + blo(a.y)*wa.z + bhi(a.y)*wa.w
        + blo(a.z)*wb.x + bhi(a.z)*wb.y + blo(a.w)*wb.z + bhi(a.w)*wb.w;
    c1 += blo(b.x)*wa.x + bhi(b.x)*wa.y + blo(b.y)*wa.z + bhi(b.y)*wa.w
        + blo(b.z)*wb.x + bhi(b.z)*wb.y + blo(b.w)*wb.z + bhi(b.w)*wb.w;
  }
  pA0 = qred(h0 + a0); pA1 = qred(h1 + a1);
  pB0 = qred(h0 + c0); pB1 = qred(h1 + c1);
}

// st1/st2: K=512, 2 rows x 2 x-streams (posterior xA / prior xB), one W stream pair.
__device__ __forceinline__ void quad2b(const u16* __restrict__ W,
                                       const float* xA, const float* xB,
                                       int n0, int n1, int l,
                                       float& pA0, float& pA1, float& pB0, float& pB1){
  const u16* w0 = W + (long)n0*512 + l*8;
  const u16* w1 = W + (long)n1*512 + l*8;
  float a0=0.f, a1=0.f, c0=0.f, c1=0.f;
  for (int j = 0; j < 16; ++j){
    const uint4 a = *(const uint4*)(w0 + 32*j);
    const uint4 b = *(const uint4*)(w1 + 32*j);
    const float4 va = ld4(xA + l*8 + 32*j);
    const float4 vb = ld4(xA + l*8 + 32*j + 4);
    const float4 wa = ld4(xB + l*8 + 32*j);
    const float4 wb = ld4(xB + l*8 + 32*j + 4);
    a0 += blo(a.x)*va.x + bhi(a.x)*va.y + blo(a.y)*va.z + bhi(a.y)*va.w
        + blo(a.z)*vb.x + bhi(a.z)*vb.y + blo(a.w)*vb.z + bhi(a.w)*vb.w;
    a1 += blo(b.x)*va.x + bhi(b.x)*va.y + blo(b.y)*va.z + bhi(b.y)*va.w
        + blo(b.z)*vb.x + bhi(b.z)*vb.y + blo(b.w)*vb.z + bhi(b.w)*vb.w;
    c0 += blo(a.x)*wa.x + bhi(a.x)*wa.y + blo(a.y)*wa.z + bhi(a.y)*wa.w
        + blo(a.z)*wb.x + bhi(a.z)*wb.y + blo(a.w)*wb.z + bhi(a.w)*wb.w;
    c1 += blo(b.x)*wa.x + bhi(b.x)*wa.y + blo(b.y)*wa.z + bhi(b.y)*wa.w
        + blo(b.z)*wb.x + bhi(b.z)*wb.y + blo(b.w)*wb.z + bhi(b.w)*wb.w;
  }
  pA0 = qred(a0); pA1 = qred(a1);
  pB0 = qred(c0); pB1 = qred(c1);
}

// ---------------- scan kernel: one block per batch row, 512 threads ------------------
// R8: exact R6 structure (proven 8563 us, VGPR 128). R7's (1024,4) forced VGPR 64 ->
// spill storm (WRITE_SIZE 3.4->11.9 GB). Only change vs R6: states written as bf16.
__global__ void __launch_bounds__(512) scan_kernel(Params p)
{
  const int tid = threadIdx.x;
  const int r = blockIdx.x;
  const int c = tid >> 2, l = tid & 3;   // 128 clusters of 4 lanes

  __shared__ __align__(16) float hs[STATE_];   // [h(512) | s(64)]
  __shared__ __align__(16) float sa[96];       // [s(64) | a(6) | 0-pad]
  __shared__ __align__(16) float ep_[EMB_];
  __shared__ __align__(16) float pe0[512], pe1[512];
  __shared__ __align__(16) float pemb[EMB_];
  __shared__ __align__(16) float gi[G3], gh[G3];
  __shared__ __align__(16) float po0[512], po1[512], pr0[512], pr1[512];
  __shared__ __align__(16) float po2[128], pr2[128];

  double klacc = 0.0;
  hs[tid] = 0.f;
  if (tid < 64) hs[512 + tid] = 0.f;
  __syncthreads();

  for (int t = 0; t < T_STEPS; ++t){
    // ---- prologue: emb_prev row + sa = [s_{t-1} | a_t | 0] ----
    {
      const long eb = ((long)(t > 0 ? t-1 : 0)*B_ + r)*EMB_;
      ep_[tid]       = p.emb[eb + tid];
      ep_[tid + 512] = p.emb[eb + 512 + tid];
      if (tid < 96){
        float v = 0.f;
        if (tid < 64)      v = hs[512 + tid];
        else if (tid < 70) v = p.action[((long)t*B_ + r)*ACT_ + (tid - 64)];
        sa[tid] = v;
      }
    }
    __syncthreads();
    // ---- S_A: pe0 (2p), gh (6p), gi (6p) — all read h/s_{t-1} ----
    for (int ps = 0; ps < 2; ++ps){
      const int n0 = ps*256 + c, n1 = n0 + 128;
      float y0, y1;
      gemv2b<STATE_>(p.bepW0, hs, n0, n1, l, y0, y1);
      if (l == 0){
        pe0[n0] = elu_f(y0 + p.epb0[n0]);
        pe0[n1] = elu_f(y1 + p.epb0[n1]);
      }
    }
    for (int ps = 0; ps < 6; ++ps){
      const int n0 = ps*256 + c, n1 = n0 + 128;
      float y0, y1;
      gemv2b<HID_>(p.bWhh, hs, n0, n1, l, y0, y1);
      if (l == 0){
        gh[n0] = y0 + p.bhh[n0];
        gh[n1] = y1 + p.bhh[n1];
      }
    }
    for (int ps = 0; ps < 6; ++ps){
      const int n0 = ps*256 + c, n1 = n0 + 128;
      float y0, y1;
      gemv2b<96>(p.bWih, sa, n0, n1, l, y0, y1);
      if (l == 0){
        gi[n0] = y0 + p.bih[n0];
        gi[n1] = y1 + p.bih[n1];
      }
    }
    __syncthreads();
    // ---- S_B: pe1 (2p) ----
    for (int ps = 0; ps < 2; ++ps){
      const int n0 = ps*256 + c, n1 = n0 + 128;
      float y0, y1;
      gemv2b<FEAT_>(p.bepW1, pe0, n0, n1, l, y0, y1);
      if (l == 0){
        pe1[n0] = elu_f(y0 + p.epb1[n0]);
        pe1[n1] = elu_f(y1 + p.epb1[n1]);
      }
    }
    __syncthreads();
    // ---- S_C: pemb (4p) + GRU combine -> h_t (disjoint LDS) ----
    for (int ps = 0; ps < 4; ++ps){
      const int n0 = ps*256 + c, n1 = n0 + 128;
      float y0, y1;
      gemv2b<FEAT_>(p.bepW2, pe1, n0, n1, l, y0, y1);
      if (l == 0){
        pemb[n0] = y0 + p.epb2[n0];
        pemb[n1] = y1 + p.epb2[n1];
      }
    }
    {
      const int j = tid;
      const float ir = gi[j], iz = gi[512+j], in_ = gi[1024+j];
      const float hr = gh[j], hz = gh[512+j], hn  = gh[1024+j];
      const float rr = sigmoid_f(ir + hr);
      const float z  = sigmoid_f(iz + hz);
      const float nn = tanhf(in_ + rr*hn);
      const float hv = (1.f - z)*nn + z*hs[j];
      hs[j] = hv;
      p.states[((long)t*B_ + r)*STATE_ + j] = f2bf(hv);
    }
    __syncthreads();
    // ---- S_D: st0 quad (2p) ----
    for (int ps = 0; ps < 2; ++ps){
      const int n0 = ps*256 + c, n1 = n0 + 128;
      float pA0, pA1, pB0, pB1;
      st0q(p.bstW0, hs, ep_, pemb, n0, n1, l, pA0, pA1, pB0, pB1);
      if (l == 0){
        po0[n0] = elu_f(pA0 + p.stb0[n0]);
        po0[n1] = elu_f(pA1 + p.stb0[n1]);
        pr0[n0] = elu_f(pB0 + p.stb0[n0]);
        pr0[n1] = elu_f(pB1 + p.stb0[n1]);
      }
    }
    __syncthreads();
    // ---- S_E: st1 quad (2p) ----
    for (int ps = 0; ps < 2; ++ps){
      const int n0 = ps*256 + c, n1 = n0 + 128;
      float pA0, pA1, pB0, pB1;
      quad2b(p.bstW1, po0, pr0, n0, n1, l, pA0, pA1, pB0, pB1);
      if (l == 0){
        po1[n0] = elu_f(pA0 + p.stb1[n0]);
        po1[n1] = elu_f(pA1 + p.stb1[n1]);
        pr1[n0] = elu_f(pB0 + p.stb1[n0]);
        pr1[n1] = elu_f(pB1 + p.stb1[n1]);
      }
    }
    __syncthreads();
    // ---- S_F: st2 quad (1p, clusters 0..63) ----
    if (c < 64){
      const int n0 = c, n1 = c + 64;
      float pA0, pA1, pB0, pB1;
      quad2b(p.bstW2, po1, pr1, n0, n1, l, pA0, pA1, pB0, pB1);
      if (l == 0){
        po2[n0] = pA0 + p.stb2[n0];
        po2[n1] = pA1 + p.stb2[n1];
        pr2[n0] = pB0 + p.stb2[n0];
        pr2[n1] = pB1 + p.stb2[n1];
      }
    }
    __syncthreads();
    // ---- S_G: KL(t) + sample s_t ----
    if (tid < 64){
      const int j = tid;
      const float qmu = po2[j],  qsr = po2[64+j];
      const float pmu = pr2[j],  psr = pr2[64+j];
      const float qstd = softplus_f(qsr) + 1e-4f;
      const float pstd = softplus_f(psr) + 1e-4f;
      const float dm = qmu - pmu;
      klacc += (double)(logf(pstd/qstd) + (qstd*qstd + dm*dm)/(2.f*pstd*pstd) - 0.5f);
      const float sv = qmu + qstd * p.eps[((long)t*B_ + r)*STOCH_ + j];
      hs[512 + j] = sv;
      p.states[((long)t*B_ + r)*STATE_ + 512 + j] = f2bf(sv);
    }
    __syncthreads();
  }

  if (tid < 64){
    const double s = wave_sum(klacc);
    if (tid == 0) atomicAdd(&p.acc[0], s);
  }
}

// ---------------- MFMA bf16 tail GEMMs (R8-new) -----------------------------------
// C = act(A[MxK]bf16 . W[NxK]bf16^T + bias). Block = 256 thr = 4 waves (2x2),
// 128x128 tile, 64x64 per wave = 4x4 frags of 16x16x32. Fragments loaded directly
// from global (weights 6 MB -> L2/L3-resident; each lane load is 16 B contiguous).
// A-frag: row = lane&15, k = (lane>>4)*8 + [0..7].  B-frag: col = lane&15, same k.
// D-frag: col = lane&15, row = (lane>>4)*4 + reg  [guide m89, HW-verified].

__global__ void __launch_bounds__(256) gemm_h_k(const u16* __restrict__ A,
                                                const u16* __restrict__ W,
                                                const float* __restrict__ bias,
                                                u16* __restrict__ Y,
                                                int NT, int K, int act)
{
  const int tid = threadIdx.x;
  const int wave = tid >> 6, lane = tid & 63;
  const int bm = blockIdx.x / NT, bn = blockIdx.x % NT;
  const int row0 = bm*128 + ((wave>>1)<<6);
  const int col0 = bn*128 + ((wave&1)<<6);
  const int lr = lane & 15, lk = (lane >> 4) * 8;
  const int N = NT << 7;
  f32x4 acc[4][4] = {};
  const u16* Ab = A + (long)row0*K + lk;
  const u16* Wb = W + (long)col0*K + lk;
  for (int k0 = 0; k0 < K; k0 += 32){
    bf16x8 a[4], b[4];
    #pragma unroll
    for (int i = 0; i < 4; ++i) a[i] = *(const bf16x8*)(Ab + (long)(16*i+lr)*K + k0);
    #pragma unroll
    for (int j = 0; j < 4; ++j) b[j] = *(const bf16x8*)(Wb + (long)(16*j+lr)*K + k0);
    #pragma unroll
    for (int i = 0; i < 4; ++i)
      #pragma unroll
      for (int j = 0; j < 4; ++j)
        acc[i][j] = __builtin_amdgcn_mfma_f32_16x16x32_bf16(a[i], b[j], acc[i][j], 0, 0, 0);
  }
  #pragma unroll
  for (int j = 0; j < 4; ++j){
    const int col = col0 + 16*j + lr;
    const float bv = bias[col];
    #pragma unroll
    for (int i = 0; i < 4; ++i){
      #pragma unroll
      for (int q = 0; q < 4; ++q){
        const int row = row0 + 16*i + (lane>>4)*4 + q;
        float v = acc[i][j][q] + bv;
        if (act) v = elu_f(v);
        Y[(long)row*N + col] = f2bf(v);
      }
    }
  }
}

__device__ __forceinline__ double wave_sum_d(double v){
  #pragma unroll
  for (int o = 32; o > 0; o >>= 1) v += __shfl_down(v, o, 64);
  return v;
}

// emb head + loss: mu = A.W^T + b; acc += sum 0.5*(tgt-mu)^2. N = 1024 (NT=8), K=512.
__global__ void __launch_bounds__(256) gemm_loss_k(const u16* __restrict__ A,
                                                   const u16* __restrict__ W,
                                                   const float* __restrict__ bias,
                                                   const float* __restrict__ tgt,
                                                   int NT, int K, double* accp)
{
  const int tid = threadIdx.x;
  const int wave = tid >> 6, lane = tid & 63;
  const int bm = blockIdx.x / NT, bn = blockIdx.x % NT;
  const int row0 = bm*128 + ((wave>>1)<<6);
  const int col0 = bn*128 + ((wave&1)<<6);
  const int lr = lane & 15, lk = (lane >> 4) * 8;
  const int N = NT << 7;
  f32x4 acc[4][4] = {};
  const u16* Ab = A + (long)row0*K + lk;
  const u16* Wb = W + (long)col0*K + lk;
  for (int k0 = 0; k0 < K; k0 += 32){
    bf16x8 a[4], b[4];
    #pragma unroll
    for (int i = 0; i < 4; ++i) a[i] = *(const bf16x8*)(Ab + (long)(16*i+lr)*K + k0);
    #pragma unroll
    for (int j = 0; j < 4; ++j) b[j] = *(const bf16x8*)(Wb + (long)(16*j+lr)*K + k0);
    #pragma unroll
    for (int i = 0; i < 4; ++i)
      #pragma unroll
      for (int j = 0; j < 4; ++j)
        acc[i][j] = __builtin_amdgcn_mfma_f32_16x16x32_bf16(a[i], b[j], acc[i][j], 0, 0, 0);
  }
  double ls = 0.0;
  #pragma unroll
  for (int j = 0; j < 4; ++j){
    const int col = col0 + 16*j + lr;
    const float bv = bias[col];
    #pragma unroll
    for (int i = 0; i < 4; ++i){
      #pragma unroll
      for (int q = 0; q < 4; ++q){
        const int row = row0 + 16*i + (lane>>4)*4 + q;
        const float d = tgt[(long)row*N + col] - (acc[i][j][q] + bv);
        ls += 0.5 * (double)d * (double)d;
      }
    }
  }
  ls = wave_sum_d(ls);
  if (lane == 0) atomicAdd(accp, ls);
}

// reward head: one-pass dot over K=512 (lane*8), bf16 h2 x fp32 W2.
__global__ void __launch_bounds__(512) rp_loss_b(const u16* __restrict__ h2,
                                                 const float* __restrict__ W2,
                                                 const float* __restrict__ b2,
                                                 const float* __restrict__ reward,
                                                 double* accp)
{
  const int tid = threadIdx.x;
  const int lane = tid & 63;
  const int wid = blockIdx.x*8 + (tid >> 6);
  double ls = 0.0;
  for (int row = wid; row < T_STEPS*B_; row += 2048) {
    const uint4 hv = *(const uint4*)(h2 + (long)row*FEAT_ + lane*8);
    const float4 w0 = ld4(W2 + lane*8);
    const float4 w1 = ld4(W2 + lane*8 + 4);
    float part = blo(hv.x)*w0.x + bhi(hv.x)*w0.y + blo(hv.y)*w0.z + bhi(hv.y)*w0.w
               + blo(hv.z)*w1.x + bhi(hv.z)*w1.y + blo(hv.w)*w1.z + bhi(hv.w)*w1.w;
    #pragma unroll
    for (int o = 32; o > 0; o >>= 1) part += __shfl_down(part, o, 64);
    if (lane == 0) {
      const float mu = part + b2[0];
      const float d = reward[row] - mu;
      ls += 0.5 * (double)d * (double)d;
    }
  }
  if (lane == 0) atomicAdd(accp, ls);
}

__global__ void final_k(const double* acc, float* out)
{
  const double tot = (acc[0] + acc[1] + acc[2]) / (double)(T_STEPS * B_)
                   + 512.0 * LOG2PI_ + 0.5 * LOG2PI_;
  out[0] = (float)tot;
}

extern "C" void kernel_launch(void* const* d_in, const int* in_sizes, int n_in,
                              void* d_out, int out_size, void* d_ws, size_t ws_size,
                              hipStream_t stream) {
  const float* emb    = (const float*)d_in[0];
  const float* action = (const float*)d_in[1];
  const float* reward = (const float*)d_in[2];
  const float* eps    = (const float*)d_in[3];
  const float* Wih  = (const float*)d_in[4];  const float* bih  = (const float*)d_in[5];
  const float* Whh  = (const float*)d_in[6];  const float* bhh  = (const float*)d_in[7];
  const float* stW0 = (const float*)d_in[8];  const float* stb0 = (const float*)d_in[9];
  const float* stW1 = (const float*)d_in[10]; const float* stb1 = (const float*)d_in[11];
  const float* stW2 = (const float*)d_in[12]; const float* stb2 = (const float*)d_in[13];
  const float* epW0 = (const float*)d_in[14]; const float* epb0 = (const float*)d_in[15];
  const float* epW1 = (const float*)d_in[16]; const float* epb1 = (const float*)d_in[17];
  const float* epW2 = (const float*)d_in[18]; const float* epb2 = (const float*)d_in[19];
  const float* rpW0 = (const float*)d_in[20]; const float* rpb0 = (const float*)d_in[21];
  const float* rpW1 = (const float*)d_in[22]; const float* rpb1 = (const float*)d_in[23];
  const float* rpW2 = (const float*)d_in[24]; const float* rpb2 = (const float*)d_in[25];

  double* acc = (double*)d_ws;
  // bf16 workspace layout (~57 MiB total, all 16B-aligned)
  u16* states_b = (u16*)((char*)d_ws + 256);          // 16384*576
  u16* h1b = states_b + (long)16384*STATE_;           // 16384*512
  u16* h2b = h1b + (long)16384*FEAT_;                 // 16384*512
  u16* bw  = h2b + (long)16384*FEAT_;
  u16* bepW0 = bw;    bw += 294912;
  u16* bepW1 = bw;    bw += 262144;
  u16* bepW2 = bw;    bw += 524288;
  u16* bWhh  = bw;    bw += 786432;
  u16* bstW0 = bw;    bw += 786432;
  u16* bstW1 = bw;    bw += 262144;
  u16* bstW2 = bw;    bw += 65536;
  u16* bWih  = bw;    bw += 147456;
  u16* brpW0 = bw;    bw += 294912;
  u16* brpW1 = bw;    bw += 262144;

  hipMemsetAsync(d_ws, 0, 256, stream);

  convw_k<<<(294912+255)/256, 256, 0, stream>>>(epW0, bepW0, 294912);
  convw_k<<<(262144+255)/256, 256, 0, stream>>>(epW1, bepW1, 262144);
  convw_k<<<(524288+255)/256, 256, 0, stream>>>(epW2, bepW2, 524288);
  convw_k<<<(786432+255)/256, 256, 0, stream>>>(Whh,  bWhh,  786432);
  convw_k<<<(786432+255)/256, 256, 0, stream>>>(stW0, bstW0, 786432);
  convw_k<<<(262144+255)/256, 256, 0, stream>>>(stW1, bstW1, 262144);
  convw_k<<<(65536+255)/256,  256, 0, stream>>>(stW2, bstW2, 65536);
  convwih_k<<<(147456+255)/256, 256, 0, stream>>>(Wih, bWih);
  convw_k<<<(294912+255)/256, 256, 0, stream>>>(rpW0, brpW0, 294912);
  convw_k<<<(262144+255)/256, 256, 0, stream>>>(rpW1, brpW1, 262144);

  Params p;
  p.emb = emb; p.action = action; p.reward = reward; p.eps = eps;
  p.bih = bih; p.bhh = bhh;
  p.stb0 = stb0; p.stb1 = stb1; p.stb2 = stb2;
  p.epb0 = epb0; p.epb1 = epb1; p.epb2 = epb2;
  p.bWih = bWih; p.bWhh = bWhh;
  p.bstW0 = bstW0; p.bstW1 = bstW1; p.bstW2 = bstW2;
  p.bepW0 = bepW0; p.bepW1 = bepW1; p.bepW2 = bepW2;
  p.states = states_b;
  p.acc = acc;
  p.out = (float*)d_out;

  scan_kernel<<<B_, 512, 0, stream>>>(p);

  // ---- ep chain: states -> h1 -> h2 -> emb loss (M=16384) ----
  gemm_h_k<<<128*4, 256, 0, stream>>>(states_b, bepW0, epb0, h1b, 4, STATE_, 1);
  gemm_h_k<<<128*4, 256, 0, stream>>>(h1b,      bepW1, epb1, h2b, 4, FEAT_, 1);
  gemm_loss_k<<<128*8, 256, 0, stream>>>(h2b, bepW2, epb2, emb, 8, FEAT_, acc + 1);
  // ---- rp chain: states -> g1 -> g2 -> reward loss (reuses h1b/h2b) ----
  gemm_h_k<<<128*4, 256, 0, stream>>>(states_b, brpW0, rpb0, h1b, 4, STATE_, 1);
  gemm_h_k<<<128*4, 256, 0, stream>>>(h1b,      brpW1, rpb1, h2b, 4, FEAT_, 1);
  rp_loss_b<<<256, 512, 0, stream>>>(h2b, rpW2, rpb2, reward, acc + 2);

  final_k<<<1, 1, 0, stream>>>(acc, p.out);
}